// Round 2
// baseline (200.790 us; speedup 1.0000x reference)
//
#include <hip/hip_runtime.h>
#include <hip/hip_fp16.h>

#define Nn   2048
#define Ff   64
#define Uu   64
#define NT   256

typedef _Float16 f16x8 __attribute__((ext_vector_type(8)));
typedef float    f32x4 __attribute__((ext_vector_type(4)));

// One block = one batch b x 16 output rows. 4 waves split the K (=2048)
// dimension into quarters; each wave computes exp(fusion) A-frags in
// registers (no LDS in main loop, no barriers), MFMAs against f16-cast X,
// and partial 16x64 G1 tiles reduce through LDS in the epilogue only.
__global__ __launch_bounds__(NT, 4) void fused_gcn(
    const float* __restrict__ X,      // [B,N,F]
    const float* __restrict__ Dyn,    // [B,N,N]
    const float* __restrict__ Wf,     // [B,N,N,3]
    const float* __restrict__ Geo,    // [N,N]
    const float* __restrict__ KLm,    // [N,N]
    const float* __restrict__ Wd,     // [F,U]
    const float* __restrict__ bdv,    // [U]
    float* __restrict__ out)          // [B,N,U]
{
    __shared__ float tiles[4][16][Ff];   // per-wave partial G1 (16 KB)
    __shared__ float wsum[4][16];
    __shared__ float inv_rowsum[16];

    const int t    = threadIdx.x;
    const int lane = t & 63;
    const int wid  = t >> 6;
    const int r    = lane & 15;          // MFMA A-row / B-col / C-col index
    const int kg   = lane >> 4;          // k-group within fragment
    const int b    = blockIdx.x >> 7;
    const int n0   = (blockIdx.x & 127) << 4;
    const int row  = n0 + r;

    const float* dRow = Dyn + ((size_t)b * Nn + row) * Nn;
    const float* wRow = Wf  + ((size_t)b * Nn + row) * (size_t)Nn * 3;
    const float* gRow = Geo + (size_t)row * Nn;
    const float* kRow = KLm + (size_t)row * Nn;
    const float* Xb   = X   + (size_t)b * Nn * Ff;

    f32x4 acc[4] = {{0,0,0,0},{0,0,0,0},{0,0,0,0},{0,0,0,0}};
    float rsum = 0.f;

    #pragma unroll 1
    for (int kb = 0; kb < 16; ++kb) {
        // this wave's k-slice base for this fragment: quarter wid, step kb
        const int mb = ((wid * 16 + kb) << 5) + (kg << 3);

        float4 da = ((const float4*)(dRow + mb))[0];
        float4 db = ((const float4*)(dRow + mb))[1];
        const float* wp = wRow + 3 * mb;
        float4 w0 = ((const float4*)wp)[0];
        float4 w1 = ((const float4*)wp)[1];
        float4 w2 = ((const float4*)wp)[2];
        float4 w3 = ((const float4*)wp)[3];
        float4 w4 = ((const float4*)wp)[4];
        float4 w5 = ((const float4*)wp)[5];
        float4 ga = ((const float4*)(gRow + mb))[0];
        float4 gb = ((const float4*)(gRow + mb))[1];
        float4 ka = ((const float4*)(kRow + mb))[0];
        float4 kc = ((const float4*)(kRow + mb))[1];

        float dv[8]  = {da.x,da.y,da.z,da.w, db.x,db.y,db.z,db.w};
        float gv[8]  = {ga.x,ga.y,ga.z,ga.w, gb.x,gb.y,gb.z,gb.w};
        float kv[8]  = {ka.x,ka.y,ka.z,ka.w, kc.x,kc.y,kc.z,kc.w};
        float wv[24] = {w0.x,w0.y,w0.z,w0.w, w1.x,w1.y,w1.z,w1.w,
                        w2.x,w2.y,w2.z,w2.w, w3.x,w3.y,w3.z,w3.w,
                        w4.x,w4.y,w4.z,w4.w, w5.x,w5.y,w5.z,w5.w};

        f16x8 af;
        #pragma unroll
        for (int j = 0; j < 8; ++j) {
            float fu = dv[j]*wv[3*j] + gv[j]*wv[3*j+1] + kv[j]*wv[3*j+2];
            _Float16 h = (_Float16)__expf(fminf(fu, 11.0f));  // never hit: |fu| ~< 6
            af[j] = h;
            rsum += (float)h;       // sum the stored (rounded) value
        }

        // 4 MFMAs cover all 64 F columns; B-frags cast from L2-resident X
        #pragma unroll
        for (int g = 0; g < 4; ++g) {
            f16x8 bf;
            #pragma unroll
            for (int j = 0; j < 8; ++j)
                bf[j] = (_Float16)Xb[(size_t)(mb + j) * Ff + (g << 4) + r];
            acc[g] = __builtin_amdgcn_mfma_f32_16x16x32_f16(af, bf, acc[g], 0, 0, 0);
        }
    }

    // ---- epilogue: reduce row sums + partial tiles across the 4 waves ----
    rsum += __shfl_xor(rsum, 16, 64);    // reduce over kg (same r)
    rsum += __shfl_xor(rsum, 32, 64);
    if (kg == 0) wsum[wid][r] = rsum;

    #pragma unroll
    for (int g = 0; g < 4; ++g)
        #pragma unroll
        for (int i = 0; i < 4; ++i)
            tiles[wid][(kg << 2) + i][(g << 4) + r] = acc[g][i];

    __syncthreads();
    if (t < 16)
        inv_rowsum[t] = 1.0f / (wsum[0][t] + wsum[1][t] + wsum[2][t] + wsum[3][t]);
    __syncthreads();

    // reduce 4 partial tiles, normalize -> g1 in tiles[0] ([16][64])
    float* base = &tiles[0][0][0];
    f32x4 s = ((const f32x4*)base)[t];
    s += ((const f32x4*)(base + 1024))[t];
    s += ((const f32x4*)(base + 2048))[t];
    s += ((const f32x4*)(base + 3072))[t];
    s *= inv_rowsum[t >> 4];
    ((f32x4*)base)[t] = s;
    __syncthreads();

    // ---- Dense(64) + tanh: wave wid handles rows wid*4..wid*4+3, col=lane
    const float* g1r = base + ((wid << 2) * Ff);
    float o0 = bdv[lane], o1 = o0, o2 = o0, o3 = o0;
    #pragma unroll 4
    for (int f = 0; f < Ff; ++f) {
        float wdv = Wd[f * Uu + lane];
        o0 += g1r[f]          * wdv;   // g1 reads are wave-uniform: LDS broadcast
        o1 += g1r[Ff + f]     * wdv;
        o2 += g1r[2*Ff + f]   * wdv;
        o3 += g1r[3*Ff + f]   * wdv;
    }
    float oo[4] = {o0, o1, o2, o3};
    #pragma unroll
    for (int i = 0; i < 4; ++i) {
        float x  = fminf(fmaxf(oo[i], -15.f), 15.f);
        float ex = __expf(2.f * x);
        out[((size_t)b * Nn + n0 + (wid << 2) + i) * Uu + lane] = (ex - 1.f) / (ex + 1.f);
    }
}

extern "C" void kernel_launch(void* const* d_in, const int* in_sizes, int n_in,
                              void* d_out, int out_size, void* d_ws, size_t ws_size,
                              hipStream_t stream) {
    const float* X   = (const float*)d_in[0];  // inputs [8,2048,64]
    const float* Dyn = (const float*)d_in[1];  // Dynamic_L [8,2048,2048]
    const float* Wf  = (const float*)d_in[2];  // W [8,2048,2048,3]
    const float* Geo = (const float*)d_in[3];  // Geo [2048,2048]
    const float* KLm = (const float*)d_in[4];  // KL [2048,2048]
    const float* Wd  = (const float*)d_in[5];  // Wd [64,64]
    const float* bdv = (const float*)d_in[6];  // bd [64]
    float* out = (float*)d_out;

    fused_gcn<<<dim3(8 * (Nn / 16)), dim3(NT), 0, stream>>>(
        X, Dyn, Wf, Geo, KLm, Wd, bdv, out);
}